// Round 11
// baseline (166.289 us; speedup 1.0000x reference)
//
#include <hip/hip_runtime.h>

#define IN_DIM 128
#define HID 64
#define SHIFT 8                 // 256 nodes per bucket
#define BNODES 256
#define NBMAX 1024              // NB=391 @ N=100k
#define CH 8192                 // edges per block (R9 lesson: 32768 -> 49 blocks = TLP collapse)
#define SRCMASK 0xFFFFF         // src packed in low 20 bits (N <= 1M)
#define LDSCAP 6144             // csr_place LDS edge-staging capacity (48 KB)

// bf16 round-to-nearest-even
__device__ inline unsigned short f2bf(float f) {
  unsigned u = __float_as_uint(f);
  u += 0x7FFF + ((u >> 16) & 1);
  return (unsigned short)(u >> 16);
}
__device__ inline float bf2f_lo(unsigned v) {   // low bf16 of a packed u32
  return __uint_as_float(v << 16);
}
__device__ inline float bf2f_hi(unsigned v) {   // high bf16 of a packed u32
  return __uint_as_float(v & 0xFFFF0000u);
}

// ---------------- Kernel 1: h1 = bf16(x @ W1 + b1)   [N,128]@[128,64] ----------------
// 64x64 tile per block, 4x4 micro-tile per thread, W1 in LDS, unroll-1 k-loop
// (R2 lesson: full unroll -> 256 VGPR + 900 MB spill traffic).
// R11: register double-buffer on the x-tiles — next iteration's 4 float4 loads
// issue before the current FMAs (R10: VALUBusy 26%, latency-bound).
// R7 lesson: do NOT fuse other stages into this kernel (replay divergence).
__global__ __launch_bounds__(256) void gemm1_kernel(
    const float* __restrict__ x, const float* __restrict__ W1,
    const float* __restrict__ b1, unsigned short* __restrict__ h1, int N) {
  __shared__ float Ws[IN_DIM][HID];
  for (int i = threadIdx.x; i < IN_DIM * HID / 4; i += 256)
    reinterpret_cast<float4*>(&Ws[0][0])[i] = reinterpret_cast<const float4*>(W1)[i];
  __syncthreads();

  const int tx = threadIdx.x & 15;
  const int ty = threadIdx.x >> 4;
  const int j0 = tx * 4;
  const int rbase = blockIdx.x * 64 + ty * 4;

  float acc[4][4];
#pragma unroll
  for (int i = 0; i < 4; ++i)
#pragma unroll
    for (int c = 0; c < 4; ++c) acc[i][c] = 0.f;

  const float4* xp[4];
#pragma unroll
  for (int i = 0; i < 4; ++i) {
    int r = rbase + i;
    if (r > N - 1) r = N - 1;
    xp[i] = reinterpret_cast<const float4*>(x + (long)r * IN_DIM);
  }

  float4 xs_cur[4];
#pragma unroll
  for (int i = 0; i < 4; ++i) xs_cur[i] = xp[i][0];

#pragma unroll 1
  for (int k4 = 0; k4 < IN_DIM / 4; ++k4) {
    // prefetch next k-tile (clamped; loads overlap this iteration's FMAs)
    const int kn = (k4 + 1 < IN_DIM / 4) ? k4 + 1 : k4;
    float4 xs_nxt[4];
#pragma unroll
    for (int i = 0; i < 4; ++i) xs_nxt[i] = xp[i][kn];

    float xs[4][4];
#pragma unroll
    for (int i = 0; i < 4; ++i)
      *reinterpret_cast<float4*>(xs[i]) = xs_cur[i];
#pragma unroll
    for (int kk = 0; kk < 4; ++kk) {
      float wv[4];
      *reinterpret_cast<float4*>(wv) =
          *reinterpret_cast<const float4*>(&Ws[k4 * 4 + kk][j0]);
#pragma unroll
      for (int i = 0; i < 4; ++i)
#pragma unroll
        for (int c = 0; c < 4; ++c)
          acc[i][c] += xs[i][kk] * wv[c];
    }
#pragma unroll
    for (int i = 0; i < 4; ++i) xs_cur[i] = xs_nxt[i];
  }

  float bb[4];
  *reinterpret_cast<float4*>(bb) = *reinterpret_cast<const float4*>(&b1[j0]);
#pragma unroll
  for (int i = 0; i < 4; ++i) {
    int r = rbase + i;
    if (r < N) {
      ushort4 o;
      o.x = f2bf(acc[i][0] + bb[0]);
      o.y = f2bf(acc[i][1] + bb[1]);
      o.z = f2bf(acc[i][2] + bb[2]);
      o.w = f2bf(acc[i][3] + bb[3]);
      *reinterpret_cast<ushort4*>(h1 + (long)r * HID + j0) = o;
    }
  }
}

// ------------- Bucket partition pass 1: per-block histogram + reservation -------------
__global__ __launch_bounds__(256) void bucket_count_kernel(
    const int* __restrict__ dst, int* __restrict__ bucket_size,
    int* __restrict__ blockRel, int NB, int E) {
  __shared__ int hist[NBMAX];
  for (int i = threadIdx.x; i < NB; i += 256) hist[i] = 0;
  __syncthreads();
  int base = blockIdx.x * CH;
  int end = min(base + CH, E);
  for (int k = base + threadIdx.x; k < end; k += 256)
    atomicAdd(&hist[dst[k] >> SHIFT], 1);
  __syncthreads();
  for (int i = threadIdx.x; i < NB; i += 256) {
    int c = hist[i];
    int r = c ? atomicAdd(&bucket_size[i], c) : 0;
    blockRel[(long)blockIdx.x * NB + i] = r;
  }
}

// ------------- Pass 2: exclusive scan of bucket sizes (single block) -------------
__global__ __launch_bounds__(1024) void bucket_scan_kernel(
    const int* __restrict__ bucket_size, int* __restrict__ bucket_offs, int NB) {
  __shared__ int tmp[1024];
  int tid = threadIdx.x;
  int v = (tid < NB) ? bucket_size[tid] : 0;
  tmp[tid] = v;
  __syncthreads();
  for (int off = 1; off < 1024; off <<= 1) {
    int t = (tid >= off) ? tmp[tid - off] : 0;
    __syncthreads();
    tmp[tid] += t;
    __syncthreads();
  }
  if (tid <= NB) bucket_offs[tid] = tmp[tid] - v;  // exclusive; offs[NB]=E
}

// ------------- Pass 3: place edges into bucket-partitioned array -------------
// Packed entry: x = src | (dst_local << 20), y = weight bits.
__global__ __launch_bounds__(256) void bucket_place_kernel(
    const int* __restrict__ src, const int* __restrict__ dst,
    const float* __restrict__ w, const int* __restrict__ bucket_offs,
    const int* __restrict__ blockRel, int2* __restrict__ bpart, int NB, int E) {
  __shared__ int cur[NBMAX];
  for (int i = threadIdx.x; i < NB; i += 256)
    cur[i] = bucket_offs[i] + blockRel[(long)blockIdx.x * NB + i];
  __syncthreads();
  int base = blockIdx.x * CH;
  int end = min(base + CH, E);
  for (int k = base + threadIdx.x; k < end; k += 256) {
    int d = dst[k];
    int b = d >> SHIFT;
    int pos = atomicAdd(&cur[b], 1);
    bpart[pos] = make_int2((src[k] & SRCMASK) | ((d & (BNODES - 1)) << 20),
                           __float_as_int(w[k]));
  }
}

// ------------- Pass 4: per-bucket CSR finalize (LDS-staged) -------------
__global__ __launch_bounds__(256) void csr_place_kernel(
    const int2* __restrict__ bpart, const int* __restrict__ bucket_offs,
    int2* __restrict__ csr, int* __restrict__ noffs, int N, int NB, int E) {
  __shared__ int cnt[BNODES];
  __shared__ int cur[BNODES];
  __shared__ int wtot[4];
  __shared__ int2 ebuf[LDSCAP];
  const int t = threadIdx.x;
  const int b = blockIdx.x;
  const int beg = bucket_offs[b], end = bucket_offs[b + 1];
  const int len = end - beg;
  const bool useLds = (len <= LDSCAP);

  cnt[t] = 0;
  __syncthreads();

  if (useLds) {
    for (int k = t; k < len; k += 256) {
      int2 e = bpart[beg + k];
      ebuf[k] = e;
      atomicAdd(&cnt[e.x >> 20], 1);
    }
  } else {
    for (int k = beg + t; k < end; k += 256)
      atomicAdd(&cnt[bpart[k].x >> 20], 1);
  }
  __syncthreads();

  // exclusive scan of cnt[0..255]: per-wave shfl scan + wave-total combine
  int v = cnt[t], s = v;
#pragma unroll
  for (int d = 1; d < 64; d <<= 1) {
    int u = __shfl_up(s, d, 64);
    if ((t & 63) >= d) s += u;
  }
  if ((t & 63) == 63) wtot[t >> 6] = s;
  __syncthreads();
  int base = 0;
  const int wv_ = t >> 6;
  if (wv_ > 0) base += wtot[0];
  if (wv_ > 1) base += wtot[1];
  if (wv_ > 2) base += wtot[2];
  const int g = beg + base + s - v;  // global exclusive offset for node t
  cur[t] = g;
  const int node = (b << SHIFT) + t;
  if (node < N) noffs[node] = g;
  if (b == NB - 1 && t == 0) noffs[N] = E;
  __syncthreads();

  if (useLds) {
    for (int k = t; k < len; k += 256) {
      int2 e = ebuf[k];
      int pos = atomicAdd(&cur[e.x >> 20], 1);
      csr[pos] = make_int2(e.x & SRCMASK, e.y);
    }
  } else {
    for (int k = beg + t; k < end; k += 256) {
      int2 e = bpart[k];
      int pos = atomicAdd(&cur[e.x >> 20], 1);
      csr[pos] = make_int2(e.x & SRCMASK, e.y);
    }
  }
}

// ---------------- Fused: h3[n] = relu(sum_e w*h1[src_e]) . W2 + b2 ----------------
// One 64-lane wave per node, four 16-lane quarters; each quarter handles one
// edge per step with ushort4 loads (4 dims / lane, 8 B/lane).
// R11: software pipeline — next pair of csr entries prefetched while the
// current gathers+FMAs run (breaks the serial csr->gather latency chain).
// Accumulation order identical to R10 (bitwise-same output).
__global__ __launch_bounds__(256) void spmm1_fused_kernel(
    const int* __restrict__ noffs, const int2* __restrict__ csr,
    const unsigned short* __restrict__ h1, const float* __restrict__ W2,
    const float* __restrict__ b2, float* __restrict__ h3, int N) {
  int wave = (blockIdx.x * 256 + threadIdx.x) >> 6;
  int lane = threadIdx.x & 63;
  if (wave >= N) return;
  int beg = noffs[wave], end = noffs[wave + 1];
  const int q   = lane >> 4;        // quarter 0..3
  const int l16 = lane & 15;        // dim group: dims 4*l16 .. 4*l16+3

  float a0 = 0.f, a1 = 0.f, a2 = 0.f, a3 = 0.f;
  int k = beg + q;

  int2 eA, eB;
  if (k + 4 < end) { eA = csr[k]; eB = csr[k + 4]; }
  while (k + 4 < end) {
    uint2 vA = *reinterpret_cast<const uint2*>(h1 + (long)eA.x * HID + 4 * l16);
    uint2 vB = *reinterpret_cast<const uint2*>(h1 + (long)eB.x * HID + 4 * l16);
    float wA = __int_as_float(eA.y), wB = __int_as_float(eB.y);
    int kn = k + 8;
    if (kn + 4 < end) { eA = csr[kn]; eB = csr[kn + 4]; }  // prefetch next pair
    a0 += wA * bf2f_lo(vA.x);
    a1 += wA * bf2f_hi(vA.x);
    a2 += wA * bf2f_lo(vA.y);
    a3 += wA * bf2f_hi(vA.y);
    a0 += wB * bf2f_lo(vB.x);
    a1 += wB * bf2f_hi(vB.x);
    a2 += wB * bf2f_lo(vB.y);
    a3 += wB * bf2f_hi(vB.y);
    k = kn;
  }
  for (; k < end; k += 4) {
    int2 e = csr[k];
    uint2 v = *reinterpret_cast<const uint2*>(h1 + (long)e.x * HID + 4 * l16);
    float w = __int_as_float(e.y);
    a0 += w * bf2f_lo(v.x);
    a1 += w * bf2f_hi(v.x);
    a2 += w * bf2f_lo(v.y);
    a3 += w * bf2f_hi(v.y);
  }

  // combine the four quarter edge-subsets
  a0 += __shfl_xor(a0, 16, 64); a0 += __shfl_xor(a0, 32, 64);
  a1 += __shfl_xor(a1, 16, 64); a1 += __shfl_xor(a1, 32, 64);
  a2 += __shfl_xor(a2, 16, 64); a2 += __shfl_xor(a2, 32, 64);
  a3 += __shfl_xor(a3, 16, 64); a3 += __shfl_xor(a3, 32, 64);

  float4 w2 = *reinterpret_cast<const float4*>(W2 + 4 * l16);
  float s = fmaxf(a0, 0.f) * w2.x + fmaxf(a1, 0.f) * w2.y +
            fmaxf(a2, 0.f) * w2.z + fmaxf(a3, 0.f) * w2.w;
  s += __shfl_xor(s, 1, 64);
  s += __shfl_xor(s, 2, 64);
  s += __shfl_xor(s, 4, 64);
  s += __shfl_xor(s, 8, 64);
  if (lane == 0) h3[wave] = s + b2[0];
}

// ---------------- Gather spmm2: out[n] = sum_e w*h3[src_e] ----------------
__global__ __launch_bounds__(256) void spmm2_gather_kernel(
    const int* __restrict__ noffs, const int2* __restrict__ csr,
    const float* __restrict__ h3, float* __restrict__ out, int N) {
  int n = blockIdx.x * 256 + threadIdx.x;
  if (n >= N) return;
  int beg = noffs[n], end = noffs[n + 1];
  float acc = 0.f;
  for (int k = beg; k < end; ++k) {
    int2 e = csr[k];
    acc += __int_as_float(e.y) * h3[e.x];
  }
  out[n] = acc;
}

extern "C" void kernel_launch(void* const* d_in, const int* in_sizes, int n_in,
                              void* d_out, int out_size, void* d_ws, size_t ws_size,
                              hipStream_t stream) {
  const float* x    = (const float*)d_in[0];
  const int*   esrc = (const int*)d_in[1];
  const int*   edst = (const int*)d_in[2];
  const float* ew   = (const float*)d_in[3];
  const float* W1   = (const float*)d_in[4];
  const float* b1   = (const float*)d_in[5];
  const float* W2   = (const float*)d_in[6];
  const float* b2   = (const float*)d_in[7];
  float* out = (float*)d_out;

  const int N = in_sizes[0] / IN_DIM;
  const int E = in_sizes[1];
  const int NB = (N + BNODES - 1) >> SHIFT;         // 391 @ N=100k
  const int PBLK = (E + CH - 1) / CH;               // 196 @ E=1.6M

  char* p = (char*)d_ws;
  auto alloc = [&](size_t bytes) {
    char* r = p;
    p += (bytes + 15) & ~(size_t)15;
    return r;
  };
  unsigned short* h1 = (unsigned short*)alloc((size_t)N * HID * sizeof(unsigned short));
  float* h3          = (float*)alloc((size_t)N * sizeof(float));
  int*   bucket_size = (int*)alloc((size_t)NB * sizeof(int));
  int*   bucket_offs = (int*)alloc((size_t)(NB + 1) * sizeof(int));
  int*   noffs       = (int*)alloc((size_t)(N + 1) * sizeof(int));
  int*   blockRel    = (int*)alloc((size_t)PBLK * NB * sizeof(int));
  int2*  bpart       = (int2*)alloc((size_t)E * sizeof(int2));
  int2*  csr         = (int2*)alloc((size_t)E * sizeof(int2));

  hipMemsetAsync(bucket_size, 0, (size_t)NB * sizeof(int), stream);

  gemm1_kernel<<<(N + 63) / 64, 256, 0, stream>>>(x, W1, b1, h1, N);

  bucket_count_kernel<<<PBLK, 256, 0, stream>>>(edst, bucket_size, blockRel, NB, E);
  bucket_scan_kernel<<<1, 1024, 0, stream>>>(bucket_size, bucket_offs, NB);
  bucket_place_kernel<<<PBLK, 256, 0, stream>>>(esrc, edst, ew, bucket_offs,
                                                blockRel, bpart, NB, E);
  csr_place_kernel<<<NB, 256, 0, stream>>>(bpart, bucket_offs, csr, noffs, N, NB, E);

  spmm1_fused_kernel<<<(unsigned)(((long)N * 64 + 255) / 256), 256, 0, stream>>>(
      noffs, csr, h1, W2, b2, h3, N);

  spmm2_gather_kernel<<<(N + 255) / 256, 256, 0, stream>>>(noffs, csr, h3, out, N);
}

// Round 12
// 160.164 us; speedup vs baseline: 1.0382x; 1.0382x over previous
//
#include <hip/hip_runtime.h>

#define IN_DIM 128
#define HID 64
#define SHIFT 8                 // 256 nodes per bucket
#define BNODES 256
#define NBMAX 1024              // NB=391 @ N=100k
#define CH 8192                 // edges per block (R9 lesson: 32768 -> 49 blocks = TLP collapse)
#define SRCMASK 0xFFFFF         // src packed in low 20 bits (N <= 1M)
#define LDSCAP 6144             // csr_place LDS edge-staging capacity (48 KB)

// bf16 round-to-nearest-even
__device__ inline unsigned short f2bf(float f) {
  unsigned u = __float_as_uint(f);
  u += 0x7FFF + ((u >> 16) & 1);
  return (unsigned short)(u >> 16);
}
__device__ inline float bf2f_lo(unsigned v) {   // low bf16 of a packed u32
  return __uint_as_float(v << 16);
}
__device__ inline float bf2f_hi(unsigned v) {   // high bf16 of a packed u32
  return __uint_as_float(v & 0xFFFF0000u);
}

// ---------------- Kernel 1: h1 = bf16(x @ W1 + b1)   [N,128]@[128,64] ----------------
// R12: fully LDS-staged. x-tile (64x128) loaded ONCE coalesced as bf16 into
// Xs[64][132] (pad 4 -> row bank offset 2; the 4 distinct rows a wave touches
// per step land on banks {b,b+8,b+16,b+24} = conflict-free broadcast).
// Kills the R11 problem: 16 tx-threads redundantly re-loading the same x rows
// from global every k-iter (16x L1 traffic, 32 KB working set = L1 thrash).
// W1 stays f32 in LDS (32 KB). 49 KB total -> 3 blocks/CU.
// R7 lesson: do NOT fuse other stages into this kernel (replay divergence).
__global__ __launch_bounds__(256) void gemm1_kernel(
    const float* __restrict__ x, const float* __restrict__ W1,
    const float* __restrict__ b1, unsigned short* __restrict__ h1, int N) {
  __shared__ float Ws[IN_DIM][HID];                 // 32 KB
  __shared__ unsigned short Xs[64][IN_DIM + 4];     // 16.9 KB bf16, padded

  for (int i = threadIdx.x; i < IN_DIM * HID / 4; i += 256)
    reinterpret_cast<float4*>(&Ws[0][0])[i] = reinterpret_cast<const float4*>(W1)[i];

  const int rblk = blockIdx.x * 64;
  for (int idx = threadIdx.x; idx < 64 * 32; idx += 256) {
    int row = idx >> 5, c4 = (idx & 31) * 4;
    int gr = rblk + row;
    if (gr > N - 1) gr = N - 1;                     // clamp loads; stores guarded
    float4 v = *reinterpret_cast<const float4*>(x + (long)gr * IN_DIM + c4);
    ushort4 o;
    o.x = f2bf(v.x); o.y = f2bf(v.y); o.z = f2bf(v.z); o.w = f2bf(v.w);
    *reinterpret_cast<ushort4*>(&Xs[row][c4]) = o;
  }
  __syncthreads();

  const int tx = threadIdx.x & 15;   // col quad: j0 = 4*tx
  const int ty = threadIdx.x >> 4;   // row group: rows 4*ty .. 4*ty+3
  const int j0 = tx * 4;

  float acc[4][4];
#pragma unroll
  for (int i = 0; i < 4; ++i)
#pragma unroll
    for (int c = 0; c < 4; ++c) acc[i][c] = 0.f;

#pragma unroll 2
  for (int k4 = 0; k4 < IN_DIM / 4; ++k4) {
    float xs[4][4];
#pragma unroll
    for (int i = 0; i < 4; ++i) {
      uint2 u = *reinterpret_cast<const uint2*>(&Xs[ty * 4 + i][k4 * 4]);
      xs[i][0] = bf2f_lo(u.x);
      xs[i][1] = bf2f_hi(u.x);
      xs[i][2] = bf2f_lo(u.y);
      xs[i][3] = bf2f_hi(u.y);
    }
#pragma unroll
    for (int kk = 0; kk < 4; ++kk) {
      float wv[4];
      *reinterpret_cast<float4*>(wv) =
          *reinterpret_cast<const float4*>(&Ws[k4 * 4 + kk][j0]);
#pragma unroll
      for (int i = 0; i < 4; ++i)
#pragma unroll
        for (int c = 0; c < 4; ++c)
          acc[i][c] += xs[i][kk] * wv[c];
    }
  }

  float bb[4];
  *reinterpret_cast<float4*>(bb) = *reinterpret_cast<const float4*>(&b1[j0]);
#pragma unroll
  for (int i = 0; i < 4; ++i) {
    int r = rblk + ty * 4 + i;
    if (r < N) {
      ushort4 o;
      o.x = f2bf(acc[i][0] + bb[0]);
      o.y = f2bf(acc[i][1] + bb[1]);
      o.z = f2bf(acc[i][2] + bb[2]);
      o.w = f2bf(acc[i][3] + bb[3]);
      *reinterpret_cast<ushort4*>(h1 + (long)r * HID + j0) = o;
    }
  }
}

// ------------- Bucket partition pass 1: per-block histogram + reservation -------------
__global__ __launch_bounds__(256) void bucket_count_kernel(
    const int* __restrict__ dst, int* __restrict__ bucket_size,
    int* __restrict__ blockRel, int NB, int E) {
  __shared__ int hist[NBMAX];
  for (int i = threadIdx.x; i < NB; i += 256) hist[i] = 0;
  __syncthreads();
  int base = blockIdx.x * CH;
  int end = min(base + CH, E);
  for (int k = base + threadIdx.x; k < end; k += 256)
    atomicAdd(&hist[dst[k] >> SHIFT], 1);
  __syncthreads();
  for (int i = threadIdx.x; i < NB; i += 256) {
    int c = hist[i];
    int r = c ? atomicAdd(&bucket_size[i], c) : 0;
    blockRel[(long)blockIdx.x * NB + i] = r;
  }
}

// ------------- Pass 2: exclusive scan of bucket sizes (single block) -------------
__global__ __launch_bounds__(1024) void bucket_scan_kernel(
    const int* __restrict__ bucket_size, int* __restrict__ bucket_offs, int NB) {
  __shared__ int tmp[1024];
  int tid = threadIdx.x;
  int v = (tid < NB) ? bucket_size[tid] : 0;
  tmp[tid] = v;
  __syncthreads();
  for (int off = 1; off < 1024; off <<= 1) {
    int t = (tid >= off) ? tmp[tid - off] : 0;
    __syncthreads();
    tmp[tid] += t;
    __syncthreads();
  }
  if (tid <= NB) bucket_offs[tid] = tmp[tid] - v;  // exclusive; offs[NB]=E
}

// ------------- Pass 3: place edges into bucket-partitioned array -------------
// Packed entry: x = src | (dst_local << 20), y = weight bits.
__global__ __launch_bounds__(256) void bucket_place_kernel(
    const int* __restrict__ src, const int* __restrict__ dst,
    const float* __restrict__ w, const int* __restrict__ bucket_offs,
    const int* __restrict__ blockRel, int2* __restrict__ bpart, int NB, int E) {
  __shared__ int cur[NBMAX];
  for (int i = threadIdx.x; i < NB; i += 256)
    cur[i] = bucket_offs[i] + blockRel[(long)blockIdx.x * NB + i];
  __syncthreads();
  int base = blockIdx.x * CH;
  int end = min(base + CH, E);
  for (int k = base + threadIdx.x; k < end; k += 256) {
    int d = dst[k];
    int b = d >> SHIFT;
    int pos = atomicAdd(&cur[b], 1);
    bpart[pos] = make_int2((src[k] & SRCMASK) | ((d & (BNODES - 1)) << 20),
                           __float_as_int(w[k]));
  }
}

// ------------- Pass 4: per-bucket CSR finalize (LDS-staged) -------------
__global__ __launch_bounds__(256) void csr_place_kernel(
    const int2* __restrict__ bpart, const int* __restrict__ bucket_offs,
    int2* __restrict__ csr, int* __restrict__ noffs, int N, int NB, int E) {
  __shared__ int cnt[BNODES];
  __shared__ int cur[BNODES];
  __shared__ int wtot[4];
  __shared__ int2 ebuf[LDSCAP];
  const int t = threadIdx.x;
  const int b = blockIdx.x;
  const int beg = bucket_offs[b], end = bucket_offs[b + 1];
  const int len = end - beg;
  const bool useLds = (len <= LDSCAP);

  cnt[t] = 0;
  __syncthreads();

  if (useLds) {
    for (int k = t; k < len; k += 256) {
      int2 e = bpart[beg + k];
      ebuf[k] = e;
      atomicAdd(&cnt[e.x >> 20], 1);
    }
  } else {
    for (int k = beg + t; k < end; k += 256)
      atomicAdd(&cnt[bpart[k].x >> 20], 1);
  }
  __syncthreads();

  // exclusive scan of cnt[0..255]: per-wave shfl scan + wave-total combine
  int v = cnt[t], s = v;
#pragma unroll
  for (int d = 1; d < 64; d <<= 1) {
    int u = __shfl_up(s, d, 64);
    if ((t & 63) >= d) s += u;
  }
  if ((t & 63) == 63) wtot[t >> 6] = s;
  __syncthreads();
  int base = 0;
  const int wv_ = t >> 6;
  if (wv_ > 0) base += wtot[0];
  if (wv_ > 1) base += wtot[1];
  if (wv_ > 2) base += wtot[2];
  const int g = beg + base + s - v;  // global exclusive offset for node t
  cur[t] = g;
  const int node = (b << SHIFT) + t;
  if (node < N) noffs[node] = g;
  if (b == NB - 1 && t == 0) noffs[N] = E;
  __syncthreads();

  if (useLds) {
    for (int k = t; k < len; k += 256) {
      int2 e = ebuf[k];
      int pos = atomicAdd(&cur[e.x >> 20], 1);
      csr[pos] = make_int2(e.x & SRCMASK, e.y);
    }
  } else {
    for (int k = beg + t; k < end; k += 256) {
      int2 e = bpart[k];
      int pos = atomicAdd(&cur[e.x >> 20], 1);
      csr[pos] = make_int2(e.x & SRCMASK, e.y);
    }
  }
}

// ---------------- Fused: h3[n] = relu(sum_e w*h1[src_e]) . W2 + b2 ----------------
// One 64-lane wave per node, four 16-lane quarters; each quarter handles one
// edge per step with ushort4 loads (4 dims / lane, 8 B/lane).
// Software pipeline on csr entries; accumulation order fixed (deterministic).
__global__ __launch_bounds__(256) void spmm1_fused_kernel(
    const int* __restrict__ noffs, const int2* __restrict__ csr,
    const unsigned short* __restrict__ h1, const float* __restrict__ W2,
    const float* __restrict__ b2, float* __restrict__ h3, int N) {
  int wave = (blockIdx.x * 256 + threadIdx.x) >> 6;
  int lane = threadIdx.x & 63;
  if (wave >= N) return;
  int beg = noffs[wave], end = noffs[wave + 1];
  const int q   = lane >> 4;        // quarter 0..3
  const int l16 = lane & 15;        // dim group: dims 4*l16 .. 4*l16+3

  float a0 = 0.f, a1 = 0.f, a2 = 0.f, a3 = 0.f;
  int k = beg + q;

  int2 eA, eB;
  if (k + 4 < end) { eA = csr[k]; eB = csr[k + 4]; }
  while (k + 4 < end) {
    uint2 vA = *reinterpret_cast<const uint2*>(h1 + (long)eA.x * HID + 4 * l16);
    uint2 vB = *reinterpret_cast<const uint2*>(h1 + (long)eB.x * HID + 4 * l16);
    float wA = __int_as_float(eA.y), wB = __int_as_float(eB.y);
    int kn = k + 8;
    if (kn + 4 < end) { eA = csr[kn]; eB = csr[kn + 4]; }  // prefetch next pair
    a0 += wA * bf2f_lo(vA.x);
    a1 += wA * bf2f_hi(vA.x);
    a2 += wA * bf2f_lo(vA.y);
    a3 += wA * bf2f_hi(vA.y);
    a0 += wB * bf2f_lo(vB.x);
    a1 += wB * bf2f_hi(vB.x);
    a2 += wB * bf2f_lo(vB.y);
    a3 += wB * bf2f_hi(vB.y);
    k = kn;
  }
  for (; k < end; k += 4) {
    int2 e = csr[k];
    uint2 v = *reinterpret_cast<const uint2*>(h1 + (long)e.x * HID + 4 * l16);
    float w = __int_as_float(e.y);
    a0 += w * bf2f_lo(v.x);
    a1 += w * bf2f_hi(v.x);
    a2 += w * bf2f_lo(v.y);
    a3 += w * bf2f_hi(v.y);
  }

  // combine the four quarter edge-subsets
  a0 += __shfl_xor(a0, 16, 64); a0 += __shfl_xor(a0, 32, 64);
  a1 += __shfl_xor(a1, 16, 64); a1 += __shfl_xor(a1, 32, 64);
  a2 += __shfl_xor(a2, 16, 64); a2 += __shfl_xor(a2, 32, 64);
  a3 += __shfl_xor(a3, 16, 64); a3 += __shfl_xor(a3, 32, 64);

  float4 w2 = *reinterpret_cast<const float4*>(W2 + 4 * l16);
  float s = fmaxf(a0, 0.f) * w2.x + fmaxf(a1, 0.f) * w2.y +
            fmaxf(a2, 0.f) * w2.z + fmaxf(a3, 0.f) * w2.w;
  s += __shfl_xor(s, 1, 64);
  s += __shfl_xor(s, 2, 64);
  s += __shfl_xor(s, 4, 64);
  s += __shfl_xor(s, 8, 64);
  if (lane == 0) h3[wave] = s + b2[0];
}

// ---------------- Gather spmm2: out[n] = sum_e w*h3[src_e] ----------------
__global__ __launch_bounds__(256) void spmm2_gather_kernel(
    const int* __restrict__ noffs, const int2* __restrict__ csr,
    const float* __restrict__ h3, float* __restrict__ out, int N) {
  int n = blockIdx.x * 256 + threadIdx.x;
  if (n >= N) return;
  int beg = noffs[n], end = noffs[n + 1];
  float acc = 0.f;
  for (int k = beg; k < end; ++k) {
    int2 e = csr[k];
    acc += __int_as_float(e.y) * h3[e.x];
  }
  out[n] = acc;
}

extern "C" void kernel_launch(void* const* d_in, const int* in_sizes, int n_in,
                              void* d_out, int out_size, void* d_ws, size_t ws_size,
                              hipStream_t stream) {
  const float* x    = (const float*)d_in[0];
  const int*   esrc = (const int*)d_in[1];
  const int*   edst = (const int*)d_in[2];
  const float* ew   = (const float*)d_in[3];
  const float* W1   = (const float*)d_in[4];
  const float* b1   = (const float*)d_in[5];
  const float* W2   = (const float*)d_in[6];
  const float* b2   = (const float*)d_in[7];
  float* out = (float*)d_out;

  const int N = in_sizes[0] / IN_DIM;
  const int E = in_sizes[1];
  const int NB = (N + BNODES - 1) >> SHIFT;         // 391 @ N=100k
  const int PBLK = (E + CH - 1) / CH;               // 196 @ E=1.6M

  char* p = (char*)d_ws;
  auto alloc = [&](size_t bytes) {
    char* r = p;
    p += (bytes + 15) & ~(size_t)15;
    return r;
  };
  unsigned short* h1 = (unsigned short*)alloc((size_t)N * HID * sizeof(unsigned short));
  float* h3          = (float*)alloc((size_t)N * sizeof(float));
  int*   bucket_size = (int*)alloc((size_t)NB * sizeof(int));
  int*   bucket_offs = (int*)alloc((size_t)(NB + 1) * sizeof(int));
  int*   noffs       = (int*)alloc((size_t)(N + 1) * sizeof(int));
  int*   blockRel    = (int*)alloc((size_t)PBLK * NB * sizeof(int));
  int2*  bpart       = (int2*)alloc((size_t)E * sizeof(int2));
  int2*  csr         = (int2*)alloc((size_t)E * sizeof(int2));

  hipMemsetAsync(bucket_size, 0, (size_t)NB * sizeof(int), stream);

  gemm1_kernel<<<(N + 63) / 64, 256, 0, stream>>>(x, W1, b1, h1, N);

  bucket_count_kernel<<<PBLK, 256, 0, stream>>>(edst, bucket_size, blockRel, NB, E);
  bucket_scan_kernel<<<1, 1024, 0, stream>>>(bucket_size, bucket_offs, NB);
  bucket_place_kernel<<<PBLK, 256, 0, stream>>>(esrc, edst, ew, bucket_offs,
                                                blockRel, bpart, NB, E);
  csr_place_kernel<<<NB, 256, 0, stream>>>(bpart, bucket_offs, csr, noffs, N, NB, E);

  spmm1_fused_kernel<<<(unsigned)(((long)N * 64 + 255) / 256), 256, 0, stream>>>(
      noffs, csr, h1, W2, b2, h3, N);

  spmm2_gather_kernel<<<(N + 255) / 256, 256, 0, stream>>>(noffs, csr, h3, out, N);
}

// Round 13
// 150.057 us; speedup vs baseline: 1.1082x; 1.0674x over previous
//
#include <hip/hip_runtime.h>

#define IN_DIM 128
#define HID 64
#define SHIFT 8                 // 256 nodes per bucket
#define BNODES 256
#define NBMAX 1024              // NB=391 @ N=100k
#define CH 4096                 // edges per block (R9: too big = TLP collapse; R13: 8192->4096, PBLK=391 > 256 CUs)
#define SRCMASK 0xFFFFF         // src packed in low 20 bits (N <= 1M)
#define LDSCAP 6144             // csr_place LDS edge-staging capacity (48 KB)

// bf16 round-to-nearest-even
__device__ inline unsigned short f2bf(float f) {
  unsigned u = __float_as_uint(f);
  u += 0x7FFF + ((u >> 16) & 1);
  return (unsigned short)(u >> 16);
}
__device__ inline float bf2f_lo(unsigned v) {   // low bf16 of a packed u32
  return __uint_as_float(v << 16);
}
__device__ inline float bf2f_hi(unsigned v) {   // high bf16 of a packed u32
  return __uint_as_float(v & 0xFFFF0000u);
}

// ---------------- Kernel 1: h1 = bf16(x @ W1 + b1)   [N,128]@[128,64] ----------------
// R12 structure: fully LDS-staged (x-tile loaded once coalesced as bf16).
// R7 lesson: do NOT fuse other stages into this kernel (replay divergence).
__global__ __launch_bounds__(256) void gemm1_kernel(
    const float* __restrict__ x, const float* __restrict__ W1,
    const float* __restrict__ b1, unsigned short* __restrict__ h1, int N) {
  __shared__ float Ws[IN_DIM][HID];                 // 32 KB
  __shared__ unsigned short Xs[64][IN_DIM + 4];     // 16.9 KB bf16, padded

  for (int i = threadIdx.x; i < IN_DIM * HID / 4; i += 256)
    reinterpret_cast<float4*>(&Ws[0][0])[i] = reinterpret_cast<const float4*>(W1)[i];

  const int rblk = blockIdx.x * 64;
  for (int idx = threadIdx.x; idx < 64 * 32; idx += 256) {
    int row = idx >> 5, c4 = (idx & 31) * 4;
    int gr = rblk + row;
    if (gr > N - 1) gr = N - 1;                     // clamp loads; stores guarded
    float4 v = *reinterpret_cast<const float4*>(x + (long)gr * IN_DIM + c4);
    ushort4 o;
    o.x = f2bf(v.x); o.y = f2bf(v.y); o.z = f2bf(v.z); o.w = f2bf(v.w);
    *reinterpret_cast<ushort4*>(&Xs[row][c4]) = o;
  }
  __syncthreads();

  const int tx = threadIdx.x & 15;   // col quad: j0 = 4*tx
  const int ty = threadIdx.x >> 4;   // row group: rows 4*ty .. 4*ty+3
  const int j0 = tx * 4;

  float acc[4][4];
#pragma unroll
  for (int i = 0; i < 4; ++i)
#pragma unroll
    for (int c = 0; c < 4; ++c) acc[i][c] = 0.f;

#pragma unroll 2
  for (int k4 = 0; k4 < IN_DIM / 4; ++k4) {
    float xs[4][4];
#pragma unroll
    for (int i = 0; i < 4; ++i) {
      uint2 u = *reinterpret_cast<const uint2*>(&Xs[ty * 4 + i][k4 * 4]);
      xs[i][0] = bf2f_lo(u.x);
      xs[i][1] = bf2f_hi(u.x);
      xs[i][2] = bf2f_lo(u.y);
      xs[i][3] = bf2f_hi(u.y);
    }
#pragma unroll
    for (int kk = 0; kk < 4; ++kk) {
      float wv[4];
      *reinterpret_cast<float4*>(wv) =
          *reinterpret_cast<const float4*>(&Ws[k4 * 4 + kk][j0]);
#pragma unroll
      for (int i = 0; i < 4; ++i)
#pragma unroll
        for (int c = 0; c < 4; ++c)
          acc[i][c] += xs[i][kk] * wv[c];
    }
  }

  float bb[4];
  *reinterpret_cast<float4*>(bb) = *reinterpret_cast<const float4*>(&b1[j0]);
#pragma unroll
  for (int i = 0; i < 4; ++i) {
    int r = rblk + ty * 4 + i;
    if (r < N) {
      ushort4 o;
      o.x = f2bf(acc[i][0] + bb[0]);
      o.y = f2bf(acc[i][1] + bb[1]);
      o.z = f2bf(acc[i][2] + bb[2]);
      o.w = f2bf(acc[i][3] + bb[3]);
      *reinterpret_cast<ushort4*>(h1 + (long)r * HID + j0) = o;
    }
  }
}

// ------------- Bucket partition pass 1: per-block histogram + reservation -------------
__global__ __launch_bounds__(256) void bucket_count_kernel(
    const int* __restrict__ dst, int* __restrict__ bucket_size,
    int* __restrict__ blockRel, int NB, int E) {
  __shared__ int hist[NBMAX];
  for (int i = threadIdx.x; i < NB; i += 256) hist[i] = 0;
  __syncthreads();
  int base = blockIdx.x * CH;
  int end = min(base + CH, E);
  for (int k = base + threadIdx.x; k < end; k += 256)
    atomicAdd(&hist[dst[k] >> SHIFT], 1);
  __syncthreads();
  for (int i = threadIdx.x; i < NB; i += 256) {
    int c = hist[i];
    int r = c ? atomicAdd(&bucket_size[i], c) : 0;
    blockRel[(long)blockIdx.x * NB + i] = r;
  }
}

// ------------- Pass 2: exclusive scan of bucket sizes (single block) -------------
__global__ __launch_bounds__(1024) void bucket_scan_kernel(
    const int* __restrict__ bucket_size, int* __restrict__ bucket_offs, int NB) {
  __shared__ int tmp[1024];
  int tid = threadIdx.x;
  int v = (tid < NB) ? bucket_size[tid] : 0;
  tmp[tid] = v;
  __syncthreads();
  for (int off = 1; off < 1024; off <<= 1) {
    int t = (tid >= off) ? tmp[tid - off] : 0;
    __syncthreads();
    tmp[tid] += t;
    __syncthreads();
  }
  if (tid <= NB) bucket_offs[tid] = tmp[tid] - v;  // exclusive; offs[NB]=E
}

// ------------- Pass 3: place edges into bucket-partitioned array -------------
// Packed entry: x = src | (dst_local << 20), y = weight bits.
__global__ __launch_bounds__(256) void bucket_place_kernel(
    const int* __restrict__ src, const int* __restrict__ dst,
    const float* __restrict__ w, const int* __restrict__ bucket_offs,
    const int* __restrict__ blockRel, int2* __restrict__ bpart, int NB, int E) {
  __shared__ int cur[NBMAX];
  for (int i = threadIdx.x; i < NB; i += 256)
    cur[i] = bucket_offs[i] + blockRel[(long)blockIdx.x * NB + i];
  __syncthreads();
  int base = blockIdx.x * CH;
  int end = min(base + CH, E);
  for (int k = base + threadIdx.x; k < end; k += 256) {
    int d = dst[k];
    int b = d >> SHIFT;
    int pos = atomicAdd(&cur[b], 1);
    bpart[pos] = make_int2((src[k] & SRCMASK) | ((d & (BNODES - 1)) << 20),
                           __float_as_int(w[k]));
  }
}

// ------------- Pass 4: per-bucket CSR finalize (LDS-staged) -------------
__global__ __launch_bounds__(256) void csr_place_kernel(
    const int2* __restrict__ bpart, const int* __restrict__ bucket_offs,
    int2* __restrict__ csr, int* __restrict__ noffs, int N, int NB, int E) {
  __shared__ int cnt[BNODES];
  __shared__ int cur[BNODES];
  __shared__ int wtot[4];
  __shared__ int2 ebuf[LDSCAP];
  const int t = threadIdx.x;
  const int b = blockIdx.x;
  const int beg = bucket_offs[b], end = bucket_offs[b + 1];
  const int len = end - beg;
  const bool useLds = (len <= LDSCAP);

  cnt[t] = 0;
  __syncthreads();

  if (useLds) {
    for (int k = t; k < len; k += 256) {
      int2 e = bpart[beg + k];
      ebuf[k] = e;
      atomicAdd(&cnt[e.x >> 20], 1);
    }
  } else {
    for (int k = beg + t; k < end; k += 256)
      atomicAdd(&cnt[bpart[k].x >> 20], 1);
  }
  __syncthreads();

  // exclusive scan of cnt[0..255]: per-wave shfl scan + wave-total combine
  int v = cnt[t], s = v;
#pragma unroll
  for (int d = 1; d < 64; d <<= 1) {
    int u = __shfl_up(s, d, 64);
    if ((t & 63) >= d) s += u;
  }
  if ((t & 63) == 63) wtot[t >> 6] = s;
  __syncthreads();
  int base = 0;
  const int wv_ = t >> 6;
  if (wv_ > 0) base += wtot[0];
  if (wv_ > 1) base += wtot[1];
  if (wv_ > 2) base += wtot[2];
  const int g = beg + base + s - v;  // global exclusive offset for node t
  cur[t] = g;
  const int node = (b << SHIFT) + t;
  if (node < N) noffs[node] = g;
  if (b == NB - 1 && t == 0) noffs[N] = E;
  __syncthreads();

  if (useLds) {
    for (int k = t; k < len; k += 256) {
      int2 e = ebuf[k];
      int pos = atomicAdd(&cur[e.x >> 20], 1);
      csr[pos] = make_int2(e.x & SRCMASK, e.y);
    }
  } else {
    for (int k = beg + t; k < end; k += 256) {
      int2 e = bpart[k];
      int pos = atomicAdd(&cur[e.x >> 20], 1);
      csr[pos] = make_int2(e.x & SRCMASK, e.y);
    }
  }
}

// ---------------- Fused: h3[n] = relu(sum_e w*h1[src_e]) . W2 + b2 ----------------
// R13: one 64-lane wave per node, EIGHT 8-lane groups; each group handles one
// edge per step with uint4 loads (8 dims / lane, 16 B/lane) -> 16 edges in
// flight per wave (2x the MLP of quarter-wave), avg-degree-16 node = 1 main
// loop iteration. Combine via 3-round butterfly-with-halving (7 shfl), then
// relu*W2 and a 6-shfl full-wave reduce. Deterministic, accumulation order
// fixed by (noffs, csr).
__global__ __launch_bounds__(256) void spmm1_fused_kernel(
    const int* __restrict__ noffs, const int2* __restrict__ csr,
    const unsigned short* __restrict__ h1, const float* __restrict__ W2,
    const float* __restrict__ b2, float* __restrict__ h3, int N) {
  int wave = (blockIdx.x * 256 + threadIdx.x) >> 6;
  int lane = threadIdx.x & 63;
  if (wave >= N) return;
  int beg = noffs[wave], end = noffs[wave + 1];
  const int e8 = lane >> 3;        // eighth 0..7 (edge subset)
  const int l8 = lane & 7;         // dim group: dims 8*l8 .. 8*l8+7

  float a0 = 0.f, a1 = 0.f, a2 = 0.f, a3 = 0.f;
  float a4 = 0.f, a5 = 0.f, a6 = 0.f, a7 = 0.f;
  int k = beg + e8;

  int2 eA, eB;
  if (k + 8 < end) { eA = csr[k]; eB = csr[k + 8]; }
  while (k + 8 < end) {
    uint4 vA = *reinterpret_cast<const uint4*>(h1 + (long)eA.x * HID + 8 * l8);
    uint4 vB = *reinterpret_cast<const uint4*>(h1 + (long)eB.x * HID + 8 * l8);
    float wA = __int_as_float(eA.y), wB = __int_as_float(eB.y);
    int kn = k + 16;
    if (kn + 8 < end) { eA = csr[kn]; eB = csr[kn + 8]; }  // prefetch next pair
    a0 += wA * bf2f_lo(vA.x); a1 += wA * bf2f_hi(vA.x);
    a2 += wA * bf2f_lo(vA.y); a3 += wA * bf2f_hi(vA.y);
    a4 += wA * bf2f_lo(vA.z); a5 += wA * bf2f_hi(vA.z);
    a6 += wA * bf2f_lo(vA.w); a7 += wA * bf2f_hi(vA.w);
    a0 += wB * bf2f_lo(vB.x); a1 += wB * bf2f_hi(vB.x);
    a2 += wB * bf2f_lo(vB.y); a3 += wB * bf2f_hi(vB.y);
    a4 += wB * bf2f_lo(vB.z); a5 += wB * bf2f_hi(vB.z);
    a6 += wB * bf2f_lo(vB.w); a7 += wB * bf2f_hi(vB.w);
    k = kn;
  }
  for (; k < end; k += 8) {
    int2 e = csr[k];
    uint4 v = *reinterpret_cast<const uint4*>(h1 + (long)e.x * HID + 8 * l8);
    float w = __int_as_float(e.y);
    a0 += w * bf2f_lo(v.x); a1 += w * bf2f_hi(v.x);
    a2 += w * bf2f_lo(v.y); a3 += w * bf2f_hi(v.y);
    a4 += w * bf2f_lo(v.z); a5 += w * bf2f_hi(v.z);
    a6 += w * bf2f_lo(v.w); a7 += w * bf2f_hi(v.w);
  }

  // Butterfly combine across eighths, halving live accs each round.
  // Round 1 (xor 8): keep dims [0..3] if e8 bit0==0 else [4..7].
  {
    const bool hi = (e8 & 1);
    float s0 = hi ? a0 : a4;  float r0 = __shfl_xor(s0, 8, 64);
    float s1 = hi ? a1 : a5;  float r1 = __shfl_xor(s1, 8, 64);
    float s2 = hi ? a2 : a6;  float r2 = __shfl_xor(s2, 8, 64);
    float s3 = hi ? a3 : a7;  float r3 = __shfl_xor(s3, 8, 64);
    a0 = (hi ? a4 : a0) + r0;
    a1 = (hi ? a5 : a1) + r1;
    a2 = (hi ? a6 : a2) + r2;
    a3 = (hi ? a7 : a3) + r3;
  }
  // Round 2 (xor 16): keep [0,1] if bit1==0 else [2,3].
  {
    const bool hi = (e8 >> 1) & 1;
    float s0 = hi ? a0 : a2;  float r0 = __shfl_xor(s0, 16, 64);
    float s1 = hi ? a1 : a3;  float r1 = __shfl_xor(s1, 16, 64);
    a0 = (hi ? a2 : a0) + r0;
    a1 = (hi ? a3 : a1) + r1;
  }
  // Round 3 (xor 32): keep [0] if bit2==0 else [1].
  {
    const bool hi = (e8 >> 2) & 1;
    float s0 = hi ? a0 : a1;  float r0 = __shfl_xor(s0, 32, 64);
    a0 = (hi ? a1 : a0) + r0;
  }
  const int dim = 8 * l8 + 4 * (e8 & 1) + 2 * ((e8 >> 1) & 1) + ((e8 >> 2) & 1);
  float s = fmaxf(a0, 0.f) * W2[dim];
  s += __shfl_xor(s, 1, 64);
  s += __shfl_xor(s, 2, 64);
  s += __shfl_xor(s, 4, 64);
  s += __shfl_xor(s, 8, 64);
  s += __shfl_xor(s, 16, 64);
  s += __shfl_xor(s, 32, 64);
  if (lane == 0) h3[wave] = s + b2[0];
}

// ---------------- Gather spmm2: out[n] = sum_e w*h3[src_e] ----------------
__global__ __launch_bounds__(256) void spmm2_gather_kernel(
    const int* __restrict__ noffs, const int2* __restrict__ csr,
    const float* __restrict__ h3, float* __restrict__ out, int N) {
  int n = blockIdx.x * 256 + threadIdx.x;
  if (n >= N) return;
  int beg = noffs[n], end = noffs[n + 1];
  float acc = 0.f;
  for (int k = beg; k < end; ++k) {
    int2 e = csr[k];
    acc += __int_as_float(e.y) * h3[e.x];
  }
  out[n] = acc;
}

extern "C" void kernel_launch(void* const* d_in, const int* in_sizes, int n_in,
                              void* d_out, int out_size, void* d_ws, size_t ws_size,
                              hipStream_t stream) {
  const float* x    = (const float*)d_in[0];
  const int*   esrc = (const int*)d_in[1];
  const int*   edst = (const int*)d_in[2];
  const float* ew   = (const float*)d_in[3];
  const float* W1   = (const float*)d_in[4];
  const float* b1   = (const float*)d_in[5];
  const float* W2   = (const float*)d_in[6];
  const float* b2   = (const float*)d_in[7];
  float* out = (float*)d_out;

  const int N = in_sizes[0] / IN_DIM;
  const int E = in_sizes[1];
  const int NB = (N + BNODES - 1) >> SHIFT;         // 391 @ N=100k
  const int PBLK = (E + CH - 1) / CH;               // 391 @ E=1.6M

  char* p = (char*)d_ws;
  auto alloc = [&](size_t bytes) {
    char* r = p;
    p += (bytes + 15) & ~(size_t)15;
    return r;
  };
  unsigned short* h1 = (unsigned short*)alloc((size_t)N * HID * sizeof(unsigned short));
  float* h3          = (float*)alloc((size_t)N * sizeof(float));
  int*   bucket_size = (int*)alloc((size_t)NB * sizeof(int));
  int*   bucket_offs = (int*)alloc((size_t)(NB + 1) * sizeof(int));
  int*   noffs       = (int*)alloc((size_t)(N + 1) * sizeof(int));
  int*   blockRel    = (int*)alloc((size_t)PBLK * NB * sizeof(int));
  int2*  bpart       = (int2*)alloc((size_t)E * sizeof(int2));
  int2*  csr         = (int2*)alloc((size_t)E * sizeof(int2));

  hipMemsetAsync(bucket_size, 0, (size_t)NB * sizeof(int), stream);

  gemm1_kernel<<<(N + 63) / 64, 256, 0, stream>>>(x, W1, b1, h1, N);

  bucket_count_kernel<<<PBLK, 256, 0, stream>>>(edst, bucket_size, blockRel, NB, E);
  bucket_scan_kernel<<<1, 1024, 0, stream>>>(bucket_size, bucket_offs, NB);
  bucket_place_kernel<<<PBLK, 256, 0, stream>>>(esrc, edst, ew, bucket_offs,
                                                blockRel, bpart, NB, E);
  csr_place_kernel<<<NB, 256, 0, stream>>>(bpart, bucket_offs, csr, noffs, N, NB, E);

  spmm1_fused_kernel<<<(unsigned)(((long)N * 64 + 255) / 256), 256, 0, stream>>>(
      noffs, csr, h1, W2, b2, h3, N);

  spmm2_gather_kernel<<<(N + 255) / 256, 256, 0, stream>>>(noffs, csr, h3, out, N);
}